// Round 14
// baseline (322.005 us; speedup 1.0000x reference)
//
#include <hip/hip_runtime.h>
#include <hip/hip_bf16.h>

typedef __attribute__((ext_vector_type(8))) short short8;
typedef __attribute__((ext_vector_type(4))) short short4_t;
typedef __attribute__((ext_vector_type(4))) float float4_t;
typedef unsigned short ushort;

#define HW 4096
#define CC 256
#define NBATCH 4
#define SEQ ((size_t)NBATCH * HW)
#define KT 32                 // keys per tile
#define NT 64                 // tiles per key-half (2048 keys)

#define GLDS(g, l) __builtin_amdgcn_global_load_lds( \
    (const __attribute__((address_space(1))) void*)(g), \
    (__attribute__((address_space(3))) void*)(l), 16, 0, 0)

static __device__ __forceinline__ unsigned short f2b(float f) {
    union { float f; unsigned u; } v; v.f = f;
    unsigned r = v.u + 0x7FFF + ((v.u >> 16) & 1);   // RNE
    return (unsigned short)(r >> 16);
}
static __device__ __forceinline__ float b2f(unsigned short u) {
    union { unsigned u; float f; } v; v.u = ((unsigned)u) << 16;
    return v.f;
}

// ---- kernel 1: x[n][c][p] -> XT[n][p][c] (bf16) and gb[n][c][p] (bf16),
//      with fused fp32->bf16 weight conversion (first 768 flat blocks). ----
__global__ __launch_bounds__(256) void k_prep(const float* __restrict__ x,
                                              const float* __restrict__ tw,
                                              const float* __restrict__ pw,
                                              const float* __restrict__ cw,
                                              unsigned short* __restrict__ XT,
                                              unsigned short* __restrict__ gb,
                                              unsigned short* __restrict__ Wbt,
                                              unsigned short* __restrict__ Wbp,
                                              unsigned short* __restrict__ Wbc) {
    __shared__ float T[64][65];
    int fb = blockIdx.x + 64 * (blockIdx.y + 4 * blockIdx.z);
    if (fb < 768) {            // 768*256 = 196608 = 3 x 256x256 weights
        int i = fb * 256 + threadIdx.x;
        int sel = i >> 16, off = i & 65535;
        const float* s = sel == 0 ? tw : (sel == 1 ? pw : cw);
        unsigned short* d = sel == 0 ? Wbt : (sel == 1 ? Wbp : Wbc);
        d[off] = f2b(s[off]);
    }
    int n = blockIdx.z, c0 = blockIdx.y * 64, p0 = blockIdx.x * 64;
    int t = threadIdx.x;
    int pl = t & 63, rg = t >> 6;
    const float* xp = x + ((size_t)n * CC + c0) * HW + p0;
    #pragma unroll
    for (int i = 0; i < 16; i++) {
        int cl = rg * 16 + i;
        float v = xp[(size_t)cl * HW + pl];
        T[cl][pl] = v;
        gb[((size_t)n * CC + c0 + cl) * HW + p0 + pl] = f2b(v);
    }
    __syncthreads();
    int cl = t & 63, pg = t >> 6;
    unsigned short* xt = XT + ((size_t)n * HW + p0) * CC + c0;
    #pragma unroll
    for (int i = 0; i < 16; i++) {
        int plw = pg * 16 + i;
        xt[(size_t)plw * CC + cl] = f2b(T[cl][plw]);
    }
}

// ---- kernel 2: projection GEMM  outT[p][co] = sum_ci XT[p][ci]*W[co][ci] + b[co] ----
__global__ __launch_bounds__(256) void k_proj(const unsigned short* __restrict__ XT,
                                              const unsigned short* __restrict__ Wt,
                                              const unsigned short* __restrict__ Wp,
                                              const float* __restrict__ bt,
                                              const float* __restrict__ bp,
                                              unsigned short* __restrict__ outT_t,
                                              unsigned short* __restrict__ outT_p) {
    const unsigned short* W; const float* b; unsigned short* outT;
    if (blockIdx.y == 0) { W = Wt; b = bt; outT = outT_t; }
    else                 { W = Wp; b = bp; outT = outT_p; }
    int w = threadIdx.x >> 6, lane = threadIdx.x & 63;
    int nidx = lane & 15, quad = lane >> 4;
    size_t row0 = (size_t)blockIdx.x * 64 + w * 16;
    float4_t acc[16];
    #pragma unroll
    for (int i = 0; i < 16; i++) acc[i] = (float4_t)(0.f);
    const unsigned short* arow = XT + (row0 + nidx) * CC + quad * 8;
    for (int ks = 0; ks < 8; ks++) {
        short8 a = *(const short8*)(arow + ks * 32);
        #pragma unroll
        for (int cb = 0; cb < 16; cb++) {
            short8 bb = *(const short8*)(W + (size_t)(cb * 16 + nidx) * CC + ks * 32 + quad * 8);
            acc[cb] = __builtin_amdgcn_mfma_f32_16x16x32_bf16(a, bb, acc[cb], 0, 0, 0);
        }
    }
    #pragma unroll
    for (int cb = 0; cb < 16; cb++) {
        int co = cb * 16 + nidx;
        float bias = b[co];
        #pragma unroll
        for (int r = 0; r < 4; r++) {
            size_t prow = row0 + quad * 4 + r;
            outT[prow * CC + co] = f2b(acc[cb][r] + bias);
        }
    }
}

// ---- kernel 3 (round-14): flash attention, TWO DECOUPLED blocks per CU.
// Q=64/block, 256 thr (4 waves), 32-key tiles, key-split 2 -> grid 512 =
// 2 blocks/CU, 2 waves/SIMD from DIFFERENT blocks: barriers don't align, so
// one block's exp/barrier/drain overlaps the other's MFMA phase (m114).
// Wave w = (qg=w>>1: 32 q) x (sub=w&1: QK 16-key slice / PV 128-ch half).
// K staged via global_load_lds direct to frag-major LDS (uniform base +
// lane*16 = GLDS's exact constraint): no staging regs, no staging VALU, no
// write conflicts. QK: A=K(LDS frags) B=theta(regs) -> packed b64 P-writes
// (r13). PV: A=V(direct global b128) B=P(LDS, conflict-free streams).
// Per-wave regs ~225 (th 64, o 64, vr 32, s 8) -> under the 256 cliff.
__global__ __launch_bounds__(256)
void k_attn(const unsigned short* __restrict__ thetaT,
            const unsigned short* __restrict__ phiT,
            const unsigned short* __restrict__ gb,
            ushort* __restrict__ Ow, float* __restrict__ lw) {
    __shared__ __align__(16) ushort Kl[2][8192];         // 16 frags x 1KB per buf, 32 KB
    __shared__ __align__(16) ushort Pbuf[2][4][64][8];   // 4 q-frags per buf, 8 KB
    __shared__ float Lbuf[2][64];

    const int tid = threadIdx.x;
    const int w = tid >> 6, lane = tid & 63;
    const int nidx = lane & 15, quad = lane >> 4;
    const int qg = w >> 1;                               // q-group (32 q)
    const int sub = w & 1;                               // key-sub (QK) / ch-half (PV)
    const int nb = (blockIdx.x & 7) >> 1;                // batch -> XCD pair
    const int h  = blockIdx.x & 1;                       // key half
    const int qtile = blockIdx.x >> 3;                   // 0..63
    const int p0 = qtile * 64;
    const size_t seq0 = (size_t)nb * HW;
    const ushort* Kg = phiT + seq0 * CC;                 // [4096][256]
    const ushort* Vg = gb + (size_t)nb * CC * HW;        // [256][4096]
    const int k00 = h * 2048;

    // persistent theta B-frags (n=q): wave's 32 queries
    short8 th[2][8];
    #pragma unroll
    for (int qs = 0; qs < 2; qs++) {
        const ushort* qrow = thetaT + (seq0 + p0 + qg * 32 + qs * 16 + nidx) * CC + quad * 8;
        #pragma unroll
        for (int kb = 0; kb < 8; kb++) th[qs][kb] = *(const short8*)(qrow + kb * 32);
    }

    float4_t o[8][2];                                    // o[mg][qt2]: ch=sub*128+mg*16+quad*4+r, q=qg*32+qt2*16+nidx
    #pragma unroll
    for (int i = 0; i < 8; i++)
        #pragma unroll
        for (int j = 0; j < 2; j++) o[i][j] = (float4_t)(0.f);
    float lrow[2] = {0.f, 0.f};

    // K staging via GLDS: wave stages frags f = w*4..w*4+3; frag f = (kgrp=f>>3, kb=f&7);
    // lane reads 16B at K[key = kgrp*16+nidx][col = kb*32 + quad*8] -> LDS f*1KB + lane*16.
    auto stageK = [&](int buf, int t) {
        #pragma unroll
        for (int i = 0; i < 4; i++) {
            const int f = w * 4 + i;
            const ushort* gp = Kg + (size_t)(k00 + t * KT + (f >> 3) * 16 + nidx) * CC
                               + (f & 7) * 32 + quad * 8;
            GLDS(gp, &Kl[buf][f * 512]);
        }
    };
    // V A-frags (m=ch): wave's 128 channels, one 32-key tile
    auto loadVregs = [&](short8 (&vr)[8], int t) {
        #pragma unroll
        for (int mg = 0; mg < 8; mg++)
            vr[mg] = *(const short8*)(Vg + (size_t)(sub * 128 + mg * 16 + nidx) * HW
                                      + k00 + t * KT + quad * 8);
    };

    const float SC = 0.0625f * 1.44269504088896f;        // /sqrt(256) * log2(e)
    // P write (from QK D: col=lane&15=q, row=quad*4+r=key within wave's 16):
    // key' = sub*16+quad*4+r -> cell = (sub*2 + (quad>>1))*16 + nidx, j0 = (quad&1)*4
    const int pcell = (sub * 2 + (quad >> 1)) * 16 + nidx;
    const int pj0 = (quad & 1) * 4;

    float4_t s0, s1;                                     // qs = 0,1
    auto expPhase = [&](int buf) {
        short4_t pk;
        #pragma unroll
        for (int r = 0; r < 4; r++) {
            float e = exp2f(s0[r] * SC); lrow[0] += e; pk[r] = (short)f2b(e);
        }
        *(short4_t*)(&Pbuf[buf][qg * 2 + 0][pcell][pj0]) = pk;
        #pragma unroll
        for (int r = 0; r < 4; r++) {
            float e = exp2f(s1[r] * SC); lrow[1] += e; pk[r] = (short)f2b(e);
        }
        *(short4_t*)(&Pbuf[buf][qg * 2 + 1][pcell][pj0]) = pk;
    };

    short8 vr[8];
    // ---- prologue ----
    stageK(0, 0);
    __syncthreads();                                     // K(0) visible
    s0 = (float4_t)(0.f); s1 = (float4_t)(0.f);
    #pragma unroll
    for (int kb = 0; kb < 8; kb++) {
        short8 kf = *(const short8*)(&Kl[0][(sub * 8 + kb) * 512 + lane * 8]);
        s0 = __builtin_amdgcn_mfma_f32_16x16x32_bf16(kf, th[0][kb], s0, 0, 0, 0);
        s1 = __builtin_amdgcn_mfma_f32_16x16x32_bf16(kf, th[1][kb], s1, 0, 0, 0);
    }
    expPhase(0);
    stageK(1, 1);
    loadVregs(vr, 0);
    __syncthreads();                                     // P(0) + K(1) ready

    // ---- main loop: iter t = PV(t) + QK(t+1) merged, one barrier ----
    #pragma unroll 1
    for (int t = 0; t < NT - 1; t++) {
        const int pb = t & 1;
        const int kbuf = (t + 1) & 1;
        short8 pf0 = *(const short8*)(&Pbuf[pb][qg * 2 + 0][lane][0]);
        short8 pf1 = *(const short8*)(&Pbuf[pb][qg * 2 + 1][lane][0]);
        s0 = (float4_t)(0.f); s1 = (float4_t)(0.f);
        #pragma unroll
        for (int i = 0; i < 8; i++) {
            short8 kf = *(const short8*)(&Kl[kbuf][(sub * 8 + i) * 512 + lane * 8]);
            s0 = __builtin_amdgcn_mfma_f32_16x16x32_bf16(kf, th[0][i], s0, 0, 0, 0);
            s1 = __builtin_amdgcn_mfma_f32_16x16x32_bf16(kf, th[1][i], s1, 0, 0, 0);
            o[i][0] = __builtin_amdgcn_mfma_f32_16x16x32_bf16(vr[i], pf0, o[i][0], 0, 0, 0);
            o[i][1] = __builtin_amdgcn_mfma_f32_16x16x32_bf16(vr[i], pf1, o[i][1], 0, 0, 0);
        }
        loadVregs(vr, t + 1);                            // WAR-safe: PV(t) consumed vr
        expPhase((t + 1) & 1);
        if (t < NT - 2) stageK(t & 1, t + 2);            // Kl[t&1] last read pre-barrier(t-1)
        __syncthreads();                                 // P(t+1) + K(t+2) ready
    }
    // ---- final PV(NT-1) ----
    {
        short8 pf0 = *(const short8*)(&Pbuf[(NT - 1) & 1][qg * 2 + 0][lane][0]);
        short8 pf1 = *(const short8*)(&Pbuf[(NT - 1) & 1][qg * 2 + 1][lane][0]);
        #pragma unroll
        for (int i = 0; i < 8; i++) {
            o[i][0] = __builtin_amdgcn_mfma_f32_16x16x32_bf16(vr[i], pf0, o[i][0], 0, 0, 0);
            o[i][1] = __builtin_amdgcn_mfma_f32_16x16x32_bf16(vr[i], pf1, o[i][1], 0, 0, 0);
        }
    }

    // ---- epilogue: partial l (reduce over quads=keys, then sub waves) ----
    #pragma unroll
    for (int qs = 0; qs < 2; qs++) {
        float v = lrow[qs];
        v += __shfl_xor(v, 16);
        v += __shfl_xor(v, 32);
        if (quad == 0) Lbuf[sub][qg * 32 + qs * 16 + nidx] = v;
    }
    __syncthreads();
    if (tid < 64)
        lw[(size_t)h * SEQ + seq0 + p0 + tid] = Lbuf[0][tid] + Lbuf[1][tid];
    // bf16 partial O: lane holds O[ch=sub*128+mg*16+quad*4+r][q=qg*32+qt2*16+nidx]
    ushort* Op = Ow + ((size_t)h * SEQ + seq0 + p0) * CC;
    #pragma unroll
    for (int mg = 0; mg < 8; mg++)
        #pragma unroll
        for (int qt2 = 0; qt2 < 2; qt2++) {
            short4_t pk;
            #pragma unroll
            for (int r = 0; r < 4; r++) pk[r] = (short)f2b(o[mg][qt2][r]);
            *(short4_t*)(Op + (size_t)(qg * 32 + qt2 * 16 + nidx) * CC
                         + sub * 128 + mg * 16 + quad * 4) = pk;
        }
}

// ---- kernel 3b: combine key-halves: fT[q][ch] = (O0+O1)/(l0+l1), bf16 in/out ----
__global__ __launch_bounds__(256) void k_reduce(const ushort* __restrict__ Ow,
                                                const float* __restrict__ lw,
                                                unsigned short* __restrict__ fT) {
    const short8* O0 = (const short8*)Ow;
    const short8* O1 = (const short8*)(Ow + SEQ * CC);
    int i0 = blockIdx.x * 256 + threadIdx.x;             // grid 512 x 4 iters, 8 elems each
    #pragma unroll
    for (int j = 0; j < 4; j++) {
        int idx = j * 131072 + i0;                       // short8 index, SEQ*CC/8 total
        int row = idx >> 5;                              // 32 short8 per 256-ch row
        float li = 1.0f / (lw[row] + lw[SEQ + row]);
        short8 a = O0[idx];
        short8 b = O1[idx];
        short8 pk;
        #pragma unroll
        for (int r = 0; r < 8; r++)
            pk[r] = (short)f2b((b2f((ushort)a[r]) + b2f((ushort)b[r])) * li);
        *(short8*)(fT + (size_t)idx * 8) = pk;
    }
}

// ---- kernel 4: out[n][co][p] = x + b[co] + sum_k W[co][k]*fT[p][k] ----
__global__ __launch_bounds__(256) void k_final(const unsigned short* __restrict__ Wc,
                                               const float* __restrict__ bc,
                                               const unsigned short* __restrict__ fT,
                                               const float* __restrict__ x,
                                               float* __restrict__ out) {
    int w = threadIdx.x >> 6, lane = threadIdx.x & 63;
    int nidx = lane & 15, quad = lane >> 4;
    int n = blockIdx.z;
    int co0 = blockIdx.y * 64 + w * 16;
    int p0 = blockIdx.x * 64;
    float4_t acc[4];
    #pragma unroll
    for (int i = 0; i < 4; i++) acc[i] = (float4_t)(0.f);
    const unsigned short* arow = Wc + (size_t)(co0 + nidx) * CC + quad * 8;
    const unsigned short* brow = fT + ((size_t)n * HW + p0 + nidx) * CC + quad * 8;
    for (int ks = 0; ks < 8; ks++) {
        short8 a = *(const short8*)(arow + ks * 32);
        #pragma unroll
        for (int pb = 0; pb < 4; pb++) {
            short8 bb = *(const short8*)(brow + (size_t)pb * 16 * CC + ks * 32);
            acc[pb] = __builtin_amdgcn_mfma_f32_16x16x32_bf16(a, bb, acc[pb], 0, 0, 0);
        }
    }
    #pragma unroll
    for (int pb = 0; pb < 4; pb++) {
        #pragma unroll
        for (int r = 0; r < 4; r++) {
            int co = co0 + quad * 4 + r;
            size_t idx = ((size_t)n * CC + co) * HW + p0 + pb * 16 + nidx;
            out[idx] = x[idx] + bc[co] + acc[pb][r];
        }
    }
}

extern "C" void kernel_launch(void* const* d_in, const int* in_sizes, int n_in,
                              void* d_out, int out_size, void* d_ws, size_t ws_size,
                              hipStream_t stream) {
    const float* x       = (const float*)d_in[0];
    const float* theta_w = (const float*)d_in[1];
    const float* theta_b = (const float*)d_in[2];
    const float* phi_w   = (const float*)d_in[3];
    const float* phi_b   = (const float*)d_in[4];
    const float* conv1_w = (const float*)d_in[5];
    const float* conv1_b = (const float*)d_in[6];
    float* out = (float*)d_out;

    unsigned short* XT  = (unsigned short*)d_ws;  // [SEQ][256] bf16
    unsigned short* gb  = XT  + SEQ * CC;         // [N][256][4096]
    unsigned short* thT = gb  + SEQ * CC;         // [SEQ][256]
    unsigned short* phT = thT + SEQ * CC;         // [SEQ][256]
    unsigned short* fT  = phT + SEQ * CC;         // [SEQ][256]
    unsigned short* Wbt = fT  + SEQ * CC;
    unsigned short* Wbp = Wbt + 65536;
    unsigned short* Wbc = Wbp + 65536;
    unsigned short* Ow  = Wbc + 65536;            // [2][SEQ][256] bf16 partial O
    float* lw = (float*)(Ow + 2 * SEQ * CC);      // [2][SEQ] fp32 partial l

    k_prep<<<dim3(64, 4, 4), 256, 0, stream>>>(x, theta_w, phi_w, conv1_w, XT, gb, Wbt, Wbp, Wbc);
    k_proj<<<dim3(256, 2), 256, 0, stream>>>(XT, Wbt, Wbp, theta_b, phi_b, thT, phT);
    k_attn<<<dim3(512), 256, 0, stream>>>(thT, phT, gb, Ow, lw);
    k_reduce<<<dim3(512), 256, 0, stream>>>(Ow, lw, fT);
    k_final<<<dim3(64, 4, 4), 256, 0, stream>>>(Wbc, conv1_b, fT, x, out);
}

// Round 15
// 210.323 us; speedup vs baseline: 1.5310x; 1.5310x over previous
//
#include <hip/hip_runtime.h>
#include <hip/hip_bf16.h>

typedef __attribute__((ext_vector_type(8))) short short8;
typedef __attribute__((ext_vector_type(4))) short short4_t;
typedef __attribute__((ext_vector_type(4))) float float4_t;
typedef unsigned short ushort;

#define HW 4096
#define CC 256
#define NBATCH 4
#define SEQ ((size_t)NBATCH * HW)

static __device__ __forceinline__ unsigned short f2b(float f) {
    union { float f; unsigned u; } v; v.f = f;
    unsigned r = v.u + 0x7FFF + ((v.u >> 16) & 1);   // RNE
    return (unsigned short)(r >> 16);
}
static __device__ __forceinline__ float b2f(unsigned short u) {
    union { unsigned u; float f; } v; v.u = ((unsigned)u) << 16;
    return v.f;
}
// packed RNE f32x2 -> bf16x2 (v_cvt_pk_bf16_f32 on gfx950)
static __device__ __forceinline__ unsigned pk2(float a, float b) {
    __hip_bfloat162 h = __float22bfloat162_rn(make_float2(a, b));
    union { __hip_bfloat162 h; unsigned u; } v; v.h = h; return v.u;
}

// ---- kernel 1: x[n][c][p] -> XT[n][p][c] (bf16) and gb[n][c][p] (bf16),
//      with fused fp32->bf16 weight conversion (first 768 flat blocks). ----
__global__ __launch_bounds__(256) void k_prep(const float* __restrict__ x,
                                              const float* __restrict__ tw,
                                              const float* __restrict__ pw,
                                              const float* __restrict__ cw,
                                              unsigned short* __restrict__ XT,
                                              unsigned short* __restrict__ gb,
                                              unsigned short* __restrict__ Wbt,
                                              unsigned short* __restrict__ Wbp,
                                              unsigned short* __restrict__ Wbc) {
    __shared__ float T[64][65];
    int fb = blockIdx.x + 64 * (blockIdx.y + 4 * blockIdx.z);
    if (fb < 768) {            // 768*256 = 196608 = 3 x 256x256 weights
        int i = fb * 256 + threadIdx.x;
        int sel = i >> 16, off = i & 65535;
        const float* s = sel == 0 ? tw : (sel == 1 ? pw : cw);
        unsigned short* d = sel == 0 ? Wbt : (sel == 1 ? Wbp : Wbc);
        d[off] = f2b(s[off]);
    }
    int n = blockIdx.z, c0 = blockIdx.y * 64, p0 = blockIdx.x * 64;
    int t = threadIdx.x;
    int pl = t & 63, rg = t >> 6;
    const float* xp = x + ((size_t)n * CC + c0) * HW + p0;
    #pragma unroll
    for (int i = 0; i < 16; i++) {
        int cl = rg * 16 + i;
        float v = xp[(size_t)cl * HW + pl];
        T[cl][pl] = v;
        gb[((size_t)n * CC + c0 + cl) * HW + p0 + pl] = f2b(v);
    }
    __syncthreads();
    int cl = t & 63, pg = t >> 6;
    unsigned short* xt = XT + ((size_t)n * HW + p0) * CC + c0;
    #pragma unroll
    for (int i = 0; i < 16; i++) {
        int plw = pg * 16 + i;
        xt[(size_t)plw * CC + cl] = f2b(T[cl][plw]);
    }
}

// ---- kernel 2: projection GEMM  outT[p][co] = sum_ci XT[p][ci]*W[co][ci] + b[co] ----
__global__ __launch_bounds__(256) void k_proj(const unsigned short* __restrict__ XT,
                                              const unsigned short* __restrict__ Wt,
                                              const unsigned short* __restrict__ Wp,
                                              const float* __restrict__ bt,
                                              const float* __restrict__ bp,
                                              unsigned short* __restrict__ outT_t,
                                              unsigned short* __restrict__ outT_p) {
    const unsigned short* W; const float* b; unsigned short* outT;
    if (blockIdx.y == 0) { W = Wt; b = bt; outT = outT_t; }
    else                 { W = Wp; b = bp; outT = outT_p; }
    int w = threadIdx.x >> 6, lane = threadIdx.x & 63;
    int nidx = lane & 15, quad = lane >> 4;
    size_t row0 = (size_t)blockIdx.x * 64 + w * 16;
    float4_t acc[16];
    #pragma unroll
    for (int i = 0; i < 16; i++) acc[i] = (float4_t)(0.f);
    const unsigned short* arow = XT + (row0 + nidx) * CC + quad * 8;
    for (int ks = 0; ks < 8; ks++) {
        short8 a = *(const short8*)(arow + ks * 32);
        #pragma unroll
        for (int cb = 0; cb < 16; cb++) {
            short8 bb = *(const short8*)(W + (size_t)(cb * 16 + nidx) * CC + ks * 32 + quad * 8);
            acc[cb] = __builtin_amdgcn_mfma_f32_16x16x32_bf16(a, bb, acc[cb], 0, 0, 0);
        }
    }
    #pragma unroll
    for (int cb = 0; cb < 16; cb++) {
        int co = cb * 16 + nidx;
        float bias = b[co];
        #pragma unroll
        for (int r = 0; r < 4; r++) {
            size_t prow = row0 + quad * 4 + r;
            outT[prow * CC + co] = f2b(acc[cb][r] + bias);
        }
    }
}

// ---- kernel 3 (round-15): r13 revert (best k_attn: 83.8us, ~820 TF eff =
// ~94% of the m97-structure plateau) + packed v_cvt_pk_bf16_f32 conversions
// in expPhase and epilogue (cuts ~50 VALU ops/thread/tile from the manual
// f2b chains). r14's Q=64 split (2x traffic, half-size MFMA phases) reverted.
__global__ __launch_bounds__(512)
void k_attn(const unsigned short* __restrict__ thetaT,
            const unsigned short* __restrict__ phiT,
            const unsigned short* __restrict__ gb,
            ushort* __restrict__ Ow, float* __restrict__ lw) {
    __shared__ __align__(16) ushort Kl[2][16384];        // frag-major, 64 KB
    __shared__ __align__(16) ushort Pbuf[2][16][64][8];  // frag-major, 32 KB
    __shared__ float Lbuf[2][128];

    const int tid = threadIdx.x;
    const int w = tid >> 6, lane = tid & 63;
    const int nidx = lane & 15, quad = lane >> 4;
    const int qg = w & 3;                                // q-group (32 q) for QK
    const int kh = w >> 2;                               // key-half (32 keys) for QK
    const int nb = (blockIdx.x & 7) >> 1;                // batch -> XCD pair
    const int h  = blockIdx.x & 1;                       // key half (kernel-level split)
    const int qtile = blockIdx.x >> 3;                   // 0..31
    const int p0 = qtile * 128;
    const size_t seq0 = (size_t)nb * HW;
    const ushort* Kg = phiT + seq0 * CC;                 // [4096][256]
    const ushort* Vg = gb + (size_t)nb * CC * HW;        // [256][4096]
    const int k00 = h * 2048;

    // persistent theta frags (B operand, n=q): wave's 32 queries
    short8 th[2][8];
    #pragma unroll
    for (int qs = 0; qs < 2; qs++) {
        const ushort* qrow = thetaT + (seq0 + p0 + qg * 32 + qs * 16 + nidx) * CC + quad * 8;
        #pragma unroll
        for (int kb = 0; kb < 8; kb++) th[qs][kb] = *(const short8*)(qrow + kb * 32);
    }

    float4_t o[2][8];                                    // ch=w*32+mg*16+quad*4+r, q=qq*16+nidx
    #pragma unroll
    for (int i = 0; i < 2; i++)
        #pragma unroll
        for (int j = 0; j < 8; j++) o[i][j] = (float4_t)(0.f);
    float lrow[2] = {0.f, 0.f};                          // q = qg*32 + qs*16 + nidx

    // K staging (conflict-free): thread -> key n_s = tid&15, chunk c_s = tid>>4
    const int c_s = tid >> 4, n_s = tid & 15;
    const int kfbase = (c_s >> 2) * 512 + ((c_s & 3) * 16 + n_s) * 8;
    auto loadKregs = [&](short8 (&kr)[4], int tt) {
        #pragma unroll
        for (int rr = 0; rr < 4; rr++)
            kr[rr] = *(const short8*)(Kg + (size_t)(k00 + tt * 64 + rr * 16 + n_s) * CC + c_s * 8);
    };
    auto stageK = [&](int buf, const short8 (&kr)[4]) {
        #pragma unroll
        for (int rr = 0; rr < 4; rr++) *(short8*)(&Kl[buf][rr * 4096 + kfbase]) = kr[rr];
    };
    auto loadVregs = [&](short8 (&vr)[4], int tt) {
        #pragma unroll
        for (int mg = 0; mg < 2; mg++)
            #pragma unroll
            for (int kst = 0; kst < 2; kst++)
                vr[mg * 2 + kst] = *(const short8*)(Vg + (size_t)(w * 32 + mg * 16 + nidx) * HW
                                                    + k00 + tt * 64 + kst * 32 + quad * 8);
    };

    const float SC = 0.0625f * 1.44269504088896f;        // /sqrt(256) * log2(e)
    // P-write cells (swapped QK): acc s[kgrp][qs] holds keys kgrp*16+quad*4+r
    // at q=nidx. Octet G = quad>>1; cell = (kgrp*2+G)*16 + (nidx ^ (G*4));
    // elem j0 = (quad&1)*4. XOR-4 swizzle spreads even/odd-quad banks.
    const int Gp = quad >> 1;
    const int pcell_lo = (nidx ^ (Gp * 4));              // low cell index part
    const int pj0 = (quad & 1) * 4;
    // P-read cell for consumer lane: octet = lane>>4, q = lane&15, same XOR
    const int prcell = ((lane >> 4) << 4) | ((lane & 15) ^ (((lane >> 4) & 1) * 4));

    float4_t s00, s01, s10, s11;                         // s[kgrp][qs]
    auto expPhase = [&](int buf) {
        {
            float e0 = exp2f(s00[0] * SC), e1 = exp2f(s00[1] * SC);
            float e2 = exp2f(s00[2] * SC), e3 = exp2f(s00[3] * SC);
            lrow[0] += (e0 + e1) + (e2 + e3);
            uint2 pk; pk.x = pk2(e0, e1); pk.y = pk2(e2, e3);
            *(uint2*)(&Pbuf[buf][(qg * 2 + 0) * 2 + kh][(0 * 2 + Gp) * 16 + pcell_lo][pj0]) = pk;
        }
        {
            float e0 = exp2f(s01[0] * SC), e1 = exp2f(s01[1] * SC);
            float e2 = exp2f(s01[2] * SC), e3 = exp2f(s01[3] * SC);
            lrow[1] += (e0 + e1) + (e2 + e3);
            uint2 pk; pk.x = pk2(e0, e1); pk.y = pk2(e2, e3);
            *(uint2*)(&Pbuf[buf][(qg * 2 + 1) * 2 + kh][(0 * 2 + Gp) * 16 + pcell_lo][pj0]) = pk;
        }
        {
            float e0 = exp2f(s10[0] * SC), e1 = exp2f(s10[1] * SC);
            float e2 = exp2f(s10[2] * SC), e3 = exp2f(s10[3] * SC);
            lrow[0] += (e0 + e1) + (e2 + e3);
            uint2 pk; pk.x = pk2(e0, e1); pk.y = pk2(e2, e3);
            *(uint2*)(&Pbuf[buf][(qg * 2 + 0) * 2 + kh][(1 * 2 + Gp) * 16 + pcell_lo][pj0]) = pk;
        }
        {
            float e0 = exp2f(s11[0] * SC), e1 = exp2f(s11[1] * SC);
            float e2 = exp2f(s11[2] * SC), e3 = exp2f(s11[3] * SC);
            lrow[1] += (e0 + e1) + (e2 + e3);
            uint2 pk; pk.x = pk2(e0, e1); pk.y = pk2(e2, e3);
            *(uint2*)(&Pbuf[buf][(qg * 2 + 1) * 2 + kh][(1 * 2 + Gp) * 16 + pcell_lo][pj0]) = pk;
        }
    };

    short8 kregs[4], vA[4], vB[4];

    // merged iteration t: PV(t)+QK(t+1) -> loads (r11/r13 placement) -> exp -> barrier
    auto ITER = [&](int t, const short8 (&vCur)[4], short8 (&vNext)[4]) {
        const int pb = t & 1;                            // P buffer for PV(t)
        const int kbuf = (t + 1) & 1;                    // Kl buffer for QK(t+1)
        s00 = (float4_t)(0.f); s01 = (float4_t)(0.f);
        s10 = (float4_t)(0.f); s11 = (float4_t)(0.f);
        #pragma unroll
        for (int i = 0; i < 8; i++) {
            short8 k0 = *(const short8*)(&Kl[kbuf][((kh * 2 + 0) * 8 + i) * 512 + lane * 8]);
            short8 k1 = *(const short8*)(&Kl[kbuf][((kh * 2 + 1) * 8 + i) * 512 + lane * 8]);
            // A = K (m=key), B = theta (n=q)
            s00 = __builtin_amdgcn_mfma_f32_16x16x32_bf16(k0, th[0][i], s00, 0, 0, 0);
            s01 = __builtin_amdgcn_mfma_f32_16x16x32_bf16(k0, th[1][i], s01, 0, 0, 0);
            s10 = __builtin_amdgcn_mfma_f32_16x16x32_bf16(k1, th[0][i], s10, 0, 0, 0);
            s11 = __builtin_amdgcn_mfma_f32_16x16x32_bf16(k1, th[1][i], s11, 0, 0, 0);
            short8 pf0 = *(const short8*)(&Pbuf[pb][i * 2 + 0][prcell][0]);
            short8 pf1 = *(const short8*)(&Pbuf[pb][i * 2 + 1][prcell][0]);
            o[0][i] = __builtin_amdgcn_mfma_f32_16x16x32_bf16(vCur[0], pf0, o[0][i], 0, 0, 0);
            o[0][i] = __builtin_amdgcn_mfma_f32_16x16x32_bf16(vCur[1], pf1, o[0][i], 0, 0, 0);
            o[1][i] = __builtin_amdgcn_mfma_f32_16x16x32_bf16(vCur[2], pf0, o[1][i], 0, 0, 0);
            o[1][i] = __builtin_amdgcn_mfma_f32_16x16x32_bf16(vCur[3], pf1, o[1][i], 0, 0, 0);
        }
        loadVregs(vNext, t + 1);                          // WAR-safe: PV(t) consumed vCur
        expPhase((t + 1) & 1);
        if (t < 30) {
            stageK((t + 2) & 1, kregs);                   // Kl[t&1] safe per barrier(t-1)
            loadKregs(kregs, (t + 3 < 32) ? t + 3 : 31);
        }
        __syncthreads();                                  // P(t+1) + Kl[t+2] ready
    };

    // ---- prologue ----
    loadKregs(kregs, 0); loadVregs(vA, 0);
    stageK(0, kregs);
    loadKregs(kregs, 1);
    __syncthreads();                                     // Kl[0] ready
    s00 = (float4_t)(0.f); s01 = (float4_t)(0.f); s10 = (float4_t)(0.f); s11 = (float4_t)(0.f);
    #pragma unroll
    for (int kb = 0; kb < 8; kb++) {
        short8 k0 = *(const short8*)(&Kl[0][((kh * 2 + 0) * 8 + kb) * 512 + lane * 8]);
        short8 k1 = *(const short8*)(&Kl[0][((kh * 2 + 1) * 8 + kb) * 512 + lane * 8]);
        s00 = __builtin_amdgcn_mfma_f32_16x16x32_bf16(k0, th[0][kb], s00, 0, 0, 0);
        s01 = __builtin_amdgcn_mfma_f32_16x16x32_bf16(k0, th[1][kb], s01, 0, 0, 0);
        s10 = __builtin_amdgcn_mfma_f32_16x16x32_bf16(k1, th[0][kb], s10, 0, 0, 0);
        s11 = __builtin_amdgcn_mfma_f32_16x16x32_bf16(k1, th[1][kb], s11, 0, 0, 0);
    }
    expPhase(0);
    stageK(1, kregs);                                    // Kl[1] = K(1)
    loadKregs(kregs, 2);
    __syncthreads();                                     // P(0) + Kl[1] ready

    // ---- main loop: 31 merged iters (even/odd static V buffers) ----
    #pragma unroll 1
    for (int tt = 0; tt < 15; tt++) {
        ITER(tt * 2, vA, vB);
        ITER(tt * 2 + 1, vB, vA);
    }
    ITER(30, vA, vB);
    // ---- final PV(31): Pbuf[1], vB = V(31) ----
    #pragma unroll
    for (int i = 0; i < 8; i++) {
        short8 pf0 = *(const short8*)(&Pbuf[1][i * 2 + 0][prcell][0]);
        short8 pf1 = *(const short8*)(&Pbuf[1][i * 2 + 1][prcell][0]);
        o[0][i] = __builtin_amdgcn_mfma_f32_16x16x32_bf16(vB[0], pf0, o[0][i], 0, 0, 0);
        o[0][i] = __builtin_amdgcn_mfma_f32_16x16x32_bf16(vB[1], pf1, o[0][i], 0, 0, 0);
        o[1][i] = __builtin_amdgcn_mfma_f32_16x16x32_bf16(vB[2], pf0, o[1][i], 0, 0, 0);
        o[1][i] = __builtin_amdgcn_mfma_f32_16x16x32_bf16(vB[3], pf1, o[1][i], 0, 0, 0);
    }

    // ---- epilogue: l (lane q=nidx; reduce over quads, then kh waves) ----
    #pragma unroll
    for (int qs = 0; qs < 2; qs++) {
        float v = lrow[qs];
        v += __shfl_xor(v, 16);
        v += __shfl_xor(v, 32);
        if (quad == 0) Lbuf[kh][qg * 32 + qs * 16 + nidx] = v;
    }
    __syncthreads();
    if (tid < 128)
        lw[(size_t)h * SEQ + seq0 + p0 + tid] = Lbuf[0][tid] + Lbuf[1][tid];
    ushort* Op = Ow + ((size_t)h * SEQ + seq0 + p0) * CC;
    #pragma unroll
    for (int mg = 0; mg < 2; mg++)
        #pragma unroll
        for (int qq = 0; qq < 8; qq++) {
            uint2 pk;
            pk.x = pk2(o[mg][qq][0], o[mg][qq][1]);
            pk.y = pk2(o[mg][qq][2], o[mg][qq][3]);
            *(uint2*)(Op + (size_t)(qq * 16 + nidx) * CC + w * 32 + mg * 16 + quad * 4) = pk;
        }
}

// ---- kernel 3b: combine key-halves: fT[q][ch] = (O0+O1)/(l0+l1), bf16 in/out ----
__global__ __launch_bounds__(256) void k_reduce(const ushort* __restrict__ Ow,
                                                const float* __restrict__ lw,
                                                unsigned short* __restrict__ fT) {
    const short8* O0 = (const short8*)Ow;
    const short8* O1 = (const short8*)(Ow + SEQ * CC);
    int i0 = blockIdx.x * 256 + threadIdx.x;             // grid 512 x 4 iters, 8 elems each
    #pragma unroll
    for (int j = 0; j < 4; j++) {
        int idx = j * 131072 + i0;                       // short8 index, SEQ*CC/8 total
        int row = idx >> 5;                              // 32 short8 per 256-ch row
        float li = 1.0f / (lw[row] + lw[SEQ + row]);
        short8 a = O0[idx];
        short8 b = O1[idx];
        short8 pk;
        #pragma unroll
        for (int r = 0; r < 8; r++)
            pk[r] = (short)f2b((b2f((ushort)a[r]) + b2f((ushort)b[r])) * li);
        *(short8*)(fT + (size_t)idx * 8) = pk;
    }
}

// ---- kernel 4: out[n][co][p] = x + b[co] + sum_k W[co][k]*fT[p][k] ----
__global__ __launch_bounds__(256) void k_final(const unsigned short* __restrict__ Wc,
                                               const float* __restrict__ bc,
                                               const unsigned short* __restrict__ fT,
                                               const float* __restrict__ x,
                                               float* __restrict__ out) {
    int w = threadIdx.x >> 6, lane = threadIdx.x & 63;
    int nidx = lane & 15, quad = lane >> 4;
    int n = blockIdx.z;
    int co0 = blockIdx.y * 64 + w * 16;
    int p0 = blockIdx.x * 64;
    float4_t acc[4];
    #pragma unroll
    for (int i = 0; i < 4; i++) acc[i] = (float4_t)(0.f);
    const unsigned short* arow = Wc + (size_t)(co0 + nidx) * CC + quad * 8;
    const unsigned short* brow = fT + ((size_t)n * HW + p0 + nidx) * CC + quad * 8;
    for (int ks = 0; ks < 8; ks++) {
        short8 a = *(const short8*)(arow + ks * 32);
        #pragma unroll
        for (int pb = 0; pb < 4; pb++) {
            short8 bb = *(const short8*)(brow + (size_t)pb * 16 * CC + ks * 32);
            acc[pb] = __builtin_amdgcn_mfma_f32_16x16x32_bf16(a, bb, acc[pb], 0, 0, 0);
        }
    }
    #pragma unroll
    for (int pb = 0; pb < 4; pb++) {
        #pragma unroll
        for (int r = 0; r < 4; r++) {
            int co = co0 + quad * 4 + r;
            size_t idx = ((size_t)n * CC + co) * HW + p0 + pb * 16 + nidx;
            out[idx] = x[idx] + bc[co] + acc[pb][r];
        }
    }
}

extern "C" void kernel_launch(void* const* d_in, const int* in_sizes, int n_in,
                              void* d_out, int out_size, void* d_ws, size_t ws_size,
                              hipStream_t stream) {
    const float* x       = (const float*)d_in[0];
    const float* theta_w = (const float*)d_in[1];
    const float* theta_b = (const float*)d_in[2];
    const float* phi_w   = (const float*)d_in[3];
    const float* phi_b   = (const float*)d_in[4];
    const float* conv1_w = (const float*)d_in[5];
    const float* conv1_b = (const float*)d_in[6];
    float* out = (float*)d_out;

    unsigned short* XT  = (unsigned short*)d_ws;  // [SEQ][256] bf16
    unsigned short* gb  = XT  + SEQ * CC;         // [N][256][4096]
    unsigned short* thT = gb  + SEQ * CC;         // [SEQ][256]
    unsigned short* phT = thT + SEQ * CC;         // [SEQ][256]
    unsigned short* fT  = phT + SEQ * CC;         // [SEQ][256]
    unsigned short* Wbt = fT  + SEQ * CC;
    unsigned short* Wbp = Wbt + 65536;
    unsigned short* Wbc = Wbp + 65536;
    unsigned short* Ow  = Wbc + 65536;            // [2][SEQ][256] bf16 partial O
    float* lw = (float*)(Ow + 2 * SEQ * CC);      // [2][SEQ] fp32 partial l

    k_prep<<<dim3(64, 4, 4), 256, 0, stream>>>(x, theta_w, phi_w, conv1_w, XT, gb, Wbt, Wbp, Wbc);
    k_proj<<<dim3(256, 2), 256, 0, stream>>>(XT, Wbt, Wbp, theta_b, phi_b, thT, phT);
    k_attn<<<dim3(256), 512, 0, stream>>>(thT, phT, gb, Ow, lw);
    k_reduce<<<dim3(512), 256, 0, stream>>>(Ow, lw, fT);
    k_final<<<dim3(64, 4, 4), 256, 0, stream>>>(Wbc, conv1_b, fT, x, out);
}